// Round 1
// baseline (543.626 us; speedup 1.0000x reference)
//
#include <hip/hip_runtime.h>

// B=8, S=512, D=1024, H=16, DK=64
typedef __bf16 bf16x8 __attribute__((ext_vector_type(8)));
typedef float  f32x4  __attribute__((ext_vector_type(4)));

__device__ __forceinline__ unsigned short f2bf(float f) {
  union { float f; unsigned u; } x; x.f = f;
  unsigned r = (x.u + 0x7FFFu + ((x.u >> 16) & 1u)) >> 16;  // RNE
  return (unsigned short)r;
}

// async global->LDS, 16B per lane; lds dest = base + lane*16 (wave-uniform base)
__device__ __forceinline__ void gload_lds16(const void* g, void* l) {
  __builtin_amdgcn_global_load_lds((__attribute__((address_space(1))) void*)g,
                                   (__attribute__((address_space(3))) void*)l,
                                   16, 0, 0);
}

// ---- fp32 -> bf16 flat convert for query & key_in (n4 float4's each) ----
__global__ void conv_kernel(const float* __restrict__ a, const float* __restrict__ b,
                            unsigned short* __restrict__ ao, unsigned short* __restrict__ bo,
                            int n4) {
  int i = blockIdx.x * 256 + threadIdx.x;
  if (i < n4) {
    float4 x = ((const float4*)a)[i];
    ushort4 y; y.x = f2bf(x.x); y.y = f2bf(x.y); y.z = f2bf(x.z); y.w = f2bf(x.w);
    ((ushort4*)ao)[i] = y;
  } else {
    int j = i - n4;
    float4 x = ((const float4*)b)[j];
    ushort4 y; y.x = f2bf(x.x); y.y = f2bf(x.y); y.z = f2bf(x.z); y.w = f2bf(x.w);
    ((ushort4*)bo)[j] = y;
  }
}

// ---- W (K,N) fp32 -> Wt (N,K) bf16, 32x32 LDS tile transpose ----
__global__ void wtrans_kernel(const float* __restrict__ Wq, const float* __restrict__ Wk,
                              unsigned short* __restrict__ Wqt, unsigned short* __restrict__ Wkt) {
  const float* W = blockIdx.z ? Wk : Wq;
  unsigned short* Wt = blockIdx.z ? Wkt : Wqt;
  __shared__ unsigned short tile[32][33];
  int k0 = blockIdx.x * 32, n0 = blockIdx.y * 32;
  int tx = threadIdx.x, ty = threadIdx.y;
  #pragma unroll
  for (int i = 0; i < 4; ++i) {
    int k = ty + i * 8;
    tile[k][tx] = f2bf(W[(size_t)(k0 + k) * 1024 + n0 + tx]);
  }
  __syncthreads();
  #pragma unroll
  for (int i = 0; i < 4; ++i) {
    int n = ty + i * 8;
    Wt[(size_t)(n0 + n) * 1024 + k0 + tx] = tile[tx][n];
  }
}

// ---- per-(b,h): asp(64), aw(64), u[b,h,d]=sum_e Wk[d,h*64+e]*aw[e], c=bk.aw ----
__global__ void prep_kernel(const float* __restrict__ aspect, const float* __restrict__ Wd,
                            const float* __restrict__ bd, const float* __restrict__ weight_m,
                            const float* __restrict__ Wk, const float* __restrict__ bk,
                            float* __restrict__ u_out, float* __restrict__ c_out) {
  int bh = blockIdx.x; int b = bh >> 4; int h = bh & 15;
  int e = threadIdx.x;  // 0..63
  __shared__ float asp_s[64];
  __shared__ float aw_s[64];
  const float* arow = aspect + (size_t)b * 1024;
  float acc = bd[e];
  for (int d = 0; d < 1024; ++d) acc += arow[d] * Wd[(size_t)d * 64 + e];
  asp_s[e] = acc;
  __syncthreads();
  float aw = 0.f;
  const float* wm = weight_m + (size_t)h * 4096;
  #pragma unroll 8
  for (int d = 0; d < 64; ++d) aw += asp_s[d] * wm[d * 64 + e];
  aw_s[e] = aw;
  __syncthreads();
  for (int d = e; d < 1024; d += 64) {
    const float* wkrow = Wk + (size_t)d * 1024 + h * 64;
    float s = 0.f;
    #pragma unroll 8
    for (int ee = 0; ee < 64; ++ee) s += wkrow[ee] * aw_s[ee];
    u_out[(size_t)bh * 1024 + d] = s;
  }
  if (e == 0) {
    float s = 0.f;
    for (int ee = 0; ee < 64; ++ee) s += bk[h * 64 + ee] * aw_s[ee];
    c_out[bh] = s;
  }
}

__global__ void lastocc_kernel(const int* __restrict__ ids, int* __restrict__ lo) {
  int b = blockIdx.x, t = threadIdx.x;
  int r = -1;
  #pragma unroll
  for (int j = 0; j < 4; ++j) if (ids[b * 4 + j] == t) r = j;
  lo[b * 512 + t] = r;
}

// ---- v[b,h,t] = tanh(key_in[b,t,:].u[b,h,:] + c[b,h] + bias_m) (fp32 exact) ----
__global__ void v_kernel(const float* __restrict__ key_in, const float* __restrict__ u,
                         const float* __restrict__ c, const float* __restrict__ bias_m,
                         float* __restrict__ v) {
  int idx = blockIdx.x * 256 + threadIdx.x;  // (b*16+h)*512 + t
  int t = idx & 511, bh = idx >> 9, b = bh >> 4;
  const float4* kr = (const float4*)(key_in + ((size_t)b * 512 + t) * 1024);
  const float4* ur = (const float4*)(u + (size_t)bh * 1024);
  float acc = 0.f;
  #pragma unroll 4
  for (int i = 0; i < 256; ++i) {
    float4 a = kr[i], w = ur[i];
    acc += a.x * w.x + a.y * w.y + a.z * w.z + a.w * w.w;
  }
  v[idx] = tanhf(acc + c[bh] + bias_m[0]);
}

// ---- a_sc fill: out[b,h,s,t] = (lt>=0 && lt>=ls) ? v[s] : v[t], float4 writes ----
__global__ void asc_kernel(const float* __restrict__ v, const int* __restrict__ lastocc,
                           float* __restrict__ out) {
  size_t i4 = (size_t)blockIdx.x * 256 + threadIdx.x;  // float4 index
  int t0 = (int)(i4 & 127) * 4;
  int s  = (int)(i4 >> 7) & 511;
  int bh = (int)(i4 >> 16);
  int b  = bh >> 4;
  const float* vrow = v + (size_t)bh * 512;
  const int*   lrow = lastocc + (size_t)b * 512;
  float vs = vrow[s];
  int   ls = lrow[s];
  float4 vt = *(const float4*)(vrow + t0);
  int4   lt = *(const int4*)(lrow + t0);
  float4 o;
  o.x = (lt.x >= 0 && lt.x >= ls) ? vs : vt.x;
  o.y = (lt.y >= 0 && lt.y >= ls) ? vs : vt.y;
  o.z = (lt.z >= 0 && lt.z >= ls) ? vs : vt.z;
  o.w = (lt.w >= 0 && lt.w >= ls) ? vs : vt.w;
  ((float4*)out)[i4] = o;
}

// ---- bf16 MFMA GEMM: C(4096x1024) = A(4096x1024) @ Bt^T, out scattered to (B,H,S,DK) bf16
// 128x128 tile, BK=32, 4 waves (2x2), each wave 64x64 via 4x4 16x16x32 MFMAs.
__global__ __launch_bounds__(256, 2)
void gemm_kernel(const unsigned short* __restrict__ Aq, const unsigned short* __restrict__ Ak,
                 const unsigned short* __restrict__ Bq, const unsigned short* __restrict__ Bk,
                 const float* __restrict__ bq, const float* __restrict__ bk,
                 unsigned short* __restrict__ qb, unsigned short* __restrict__ kb) {
  const unsigned short* A  = blockIdx.z ? Ak : Aq;
  const unsigned short* Bt = blockIdx.z ? Bk : Bq;
  const float* bias = blockIdx.z ? bk : bq;
  unsigned short* out = blockIdx.z ? kb : qb;
  const int m0 = blockIdx.y * 128, n0 = blockIdx.x * 128;
  __shared__ __align__(16) unsigned short As[128 * 32];  // 8 KB, row-major, no pad
  __shared__ __align__(16) unsigned short Bs[128 * 32];
  const int tid = threadIdx.x, wid = tid >> 6, lane = tid & 63;
  const int wr = wid >> 1, wc = wid & 1;
  const int quad = lane >> 4, l15 = lane & 15;
  const int rstage = lane >> 2;        // 16 rows per 1KB chunk
  const int kc = (lane & 3) * 8;
  f32x4 acc[4][4] = {};
  for (int k0 = 0; k0 < 1024; k0 += 32) {
    #pragma unroll
    for (int i = 0; i < 2; ++i) {
      int row = wid * 32 + i * 16 + rstage;
      gload_lds16(A  + (size_t)(m0 + row) * 1024 + k0 + kc, As + (wid * 32 + i * 16) * 32);
      gload_lds16(Bt + (size_t)(n0 + row) * 1024 + k0 + kc, Bs + (wid * 32 + i * 16) * 32);
    }
    __syncthreads();
    bf16x8 af[4], bf[4];
    #pragma unroll
    for (int mi = 0; mi < 4; ++mi)
      af[mi] = *(const bf16x8*)(As + (wr * 64 + mi * 16 + l15) * 32 + quad * 8);
    #pragma unroll
    for (int ni = 0; ni < 4; ++ni)
      bf[ni] = *(const bf16x8*)(Bs + (wc * 64 + ni * 16 + l15) * 32 + quad * 8);
    #pragma unroll
    for (int mi = 0; mi < 4; ++mi)
      #pragma unroll
      for (int ni = 0; ni < 4; ++ni)
        acc[mi][ni] = __builtin_amdgcn_mfma_f32_16x16x32_bf16(af[mi], bf[ni], acc[mi][ni], 0, 0, 0);
    __syncthreads();
  }
  // epilogue: C/D layout col=lane&15, row=quad*4+r; scatter to (B,H,S,DK) bf16 + bias
  #pragma unroll
  for (int mi = 0; mi < 4; ++mi) {
    #pragma unroll
    for (int ni = 0; ni < 4; ++ni) {
      const int n = n0 + wc * 64 + ni * 16 + l15;
      const int hh = n >> 6, dk = n & 63;
      const float bv = bias[n];
      #pragma unroll
      for (int r = 0; r < 4; ++r) {
        const int m = m0 + wr * 64 + mi * 16 + quad * 4 + r;
        const int bb = m >> 9, ss = m & 511;
        out[(((size_t)bb * 16 + hh) * 512 + ss) * 64 + dk] = f2bf(acc[mi][ni][r] + bv);
      }
    }
  }
}

// ---- scores + mask + softmax: block = (b,h,64 s-rows), wave = 16 rows x 512 cols ----
__global__ __launch_bounds__(256, 2)
void attn_kernel(const unsigned short* __restrict__ qb, const unsigned short* __restrict__ kb,
                 const int* __restrict__ mask, float* __restrict__ attn) {
  __shared__ __align__(16) unsigned short ks[256 * 64];  // 32 KB (half of k slab)
  __shared__ __align__(16) unsigned short qs[64 * 64];   // 8 KB
  const int s0 = blockIdx.x * 64;
  const int h = blockIdx.y, b = blockIdx.z, bh = b * 16 + h;
  const int tid = threadIdx.x, wid = tid >> 6, lane = tid & 63;
  const int quad = lane >> 4, l15 = lane & 15;
  const unsigned short* kslab = kb + (size_t)bh * 512 * 64;
  const unsigned short* qslab = qb + ((size_t)bh * 512 + s0) * 64;
  #pragma unroll
  for (int i = 0; i < 2; ++i)
    gload_lds16(qslab + (wid * 2 + i) * 512 + lane * 8, qs + (wid * 2 + i) * 512);
  #pragma unroll
  for (int i = 0; i < 8; ++i)
    gload_lds16(kslab + (wid * 8 + i) * 512 + lane * 8, ks + (wid * 8 + i) * 512);
  __syncthreads();
  bf16x8 af0 = *(const bf16x8*)(qs + (wid * 16 + l15) * 64 + quad * 8);
  bf16x8 af1 = *(const bf16x8*)(qs + (wid * 16 + l15) * 64 + 32 + quad * 8);
  f32x4 acc[32];
  #pragma unroll
  for (int tile = 0; tile < 16; ++tile) {
    bf16x8 b0 = *(const bf16x8*)(ks + (tile * 16 + l15) * 64 + quad * 8);
    bf16x8 b1 = *(const bf16x8*)(ks + (tile * 16 + l15) * 64 + 32 + quad * 8);
    f32x4 a = {0.f, 0.f, 0.f, 0.f};
    a = __builtin_amdgcn_mfma_f32_16x16x32_bf16(af0, b0, a, 0, 0, 0);
    a = __builtin_amdgcn_mfma_f32_16x16x32_bf16(af1, b1, a, 0, 0, 0);
    acc[tile] = a;
  }
  __syncthreads();
  #pragma unroll
  for (int i = 0; i < 8; ++i)
    gload_lds16(kslab + 16384 + (wid * 8 + i) * 512 + lane * 8, ks + (wid * 8 + i) * 512);
  __syncthreads();
  #pragma unroll
  for (int tile = 16; tile < 32; ++tile) {
    int tl = tile - 16;
    bf16x8 b0 = *(const bf16x8*)(ks + (tl * 16 + l15) * 64 + quad * 8);
    bf16x8 b1 = *(const bf16x8*)(ks + (tl * 16 + l15) * 64 + 32 + quad * 8);
    f32x4 a = {0.f, 0.f, 0.f, 0.f};
    a = __builtin_amdgcn_mfma_f32_16x16x32_bf16(af0, b0, a, 0, 0, 0);
    a = __builtin_amdgcn_mfma_f32_16x16x32_bf16(af1, b1, a, 0, 0, 0);
    acc[tile] = a;
  }
  // scale + mask + row-max (row = s0 + wid*16 + quad*4 + r, col = tile*16 + l15)
  const size_t srow = (size_t)s0 + wid * 16 + quad * 4;
  const int* mbase = mask + ((size_t)b * 512 + srow) * 512 + l15;
  float mx[4] = {-3.0e38f, -3.0e38f, -3.0e38f, -3.0e38f};
  #pragma unroll
  for (int tile = 0; tile < 32; ++tile)
    #pragma unroll
    for (int r = 0; r < 4; ++r) {
      float sc = acc[tile][r] * 0.125f;
      int mv = mbase[(size_t)r * 512 + tile * 16];
      sc = (mv == 0) ? -1.0e9f : sc;
      acc[tile][r] = sc;
      mx[r] = fmaxf(mx[r], sc);
    }
  #pragma unroll
  for (int r = 0; r < 4; ++r)
    #pragma unroll
    for (int off = 1; off < 16; off <<= 1)
      mx[r] = fmaxf(mx[r], __shfl_xor(mx[r], off, 64));
  float sm[4] = {0.f, 0.f, 0.f, 0.f};
  #pragma unroll
  for (int tile = 0; tile < 32; ++tile)
    #pragma unroll
    for (int r = 0; r < 4; ++r) {
      float e = __expf(acc[tile][r] - mx[r]);
      acc[tile][r] = e;
      sm[r] += e;
    }
  #pragma unroll
  for (int r = 0; r < 4; ++r) {
    #pragma unroll
    for (int off = 1; off < 16; off <<= 1)
      sm[r] += __shfl_xor(sm[r], off, 64);
    sm[r] = 1.0f / sm[r];
  }
  float* obase = attn + ((size_t)bh * 512 + srow) * 512 + l15;
  #pragma unroll
  for (int r = 0; r < 4; ++r)
    #pragma unroll
    for (int tile = 0; tile < 32; ++tile)
      obase[(size_t)r * 512 + tile * 16] = acc[tile][r] * sm[r];
}

extern "C" void kernel_launch(void* const* d_in, const int* in_sizes, int n_in,
                              void* d_out, int out_size, void* d_ws, size_t ws_size,
                              hipStream_t stream) {
  const float* query    = (const float*)d_in[0];
  const float* key_in   = (const float*)d_in[1];
  const int*   mask     = (const int*)d_in[2];
  const float* aspect   = (const float*)d_in[3];
  const int*   a_ids    = (const int*)d_in[4];
  const float* Wq       = (const float*)d_in[5];
  const float* bq       = (const float*)d_in[6];
  const float* Wk       = (const float*)d_in[7];
  const float* bk       = (const float*)d_in[8];
  const float* Wd       = (const float*)d_in[9];
  const float* bd       = (const float*)d_in[10];
  const float* weight_m = (const float*)d_in[11];
  const float* bias_m   = (const float*)d_in[12];

  float* out_asc  = (float*)d_out;
  float* out_attn = out_asc + 33554432ull;  // B*H*S*S

  char* ws = (char*)d_ws;                              // ~38.6 MB used
  unsigned short* Aq   = (unsigned short*)(ws);                 // 8 MB  bf16 query
  unsigned short* Ak   = (unsigned short*)(ws + 8388608);       // 8 MB  bf16 key_in
  unsigned short* Wqt  = (unsigned short*)(ws + 16777216);      // 2 MB  bf16 Wq^T
  unsigned short* Wkt  = (unsigned short*)(ws + 18874368);      // 2 MB  bf16 Wk^T
  unsigned short* qbuf = (unsigned short*)(ws + 20971520);      // 8 MB  q (B,H,S,DK) bf16
  unsigned short* kbuf = (unsigned short*)(ws + 29360128);      // 8 MB  k (B,H,S,DK) bf16
  float* u   = (float*)(ws + 37748736);                         // 512 KB
  float* c   = (float*)(ws + 38273024);                         // 4 KB pad
  float* v   = (float*)(ws + 38277120);                         // 256 KB
  int*   lo  = (int*)  (ws + 38539264);                         // 16 KB

  conv_kernel<<<dim3(8192), dim3(256), 0, stream>>>(query, key_in, Aq, Ak, 1048576);
  wtrans_kernel<<<dim3(32, 32, 2), dim3(32, 8), 0, stream>>>(Wq, Wk, Wqt, Wkt);
  prep_kernel<<<dim3(128), dim3(64), 0, stream>>>(aspect, Wd, bd, weight_m, Wk, bk, u, c);
  lastocc_kernel<<<dim3(8), dim3(512), 0, stream>>>(a_ids, lo);
  gemm_kernel<<<dim3(8, 32, 2), dim3(256), 0, stream>>>(Aq, Ak, Wqt, Wkt, bq, bk, qbuf, kbuf);
  v_kernel<<<dim3(256), dim3(256), 0, stream>>>(key_in, u, c, bias_m, v);
  asc_kernel<<<dim3(32768), dim3(256), 0, stream>>>(v, lo, out_asc);
  attn_kernel<<<dim3(8, 16, 8), dim3(256), 0, stream>>>(qbuf, kbuf, mask, out_attn);
}

// Round 2
// 487.830 us; speedup vs baseline: 1.1144x; 1.1144x over previous
//
#include <hip/hip_runtime.h>

// B=8, S=512, D=1024, H=16, DK=64
typedef __bf16 bf16x8 __attribute__((ext_vector_type(8)));
typedef float  f32x4  __attribute__((ext_vector_type(4)));

__device__ __forceinline__ unsigned short f2bf(float f) {
  union { float f; unsigned u; } x; x.f = f;
  unsigned r = (x.u + 0x7FFFu + ((x.u >> 16) & 1u)) >> 16;  // RNE
  return (unsigned short)r;
}

__device__ __forceinline__ void gload_lds16(const void* g, void* l) {
  __builtin_amdgcn_global_load_lds((__attribute__((address_space(1))) void*)g,
                                   (__attribute__((address_space(3))) void*)l,
                                   16, 0, 0);
}

// ---- fp32 -> bf16 flat convert for query & key_in (n4 float4's each) ----
__global__ void conv_kernel(const float* __restrict__ a, const float* __restrict__ b,
                            unsigned short* __restrict__ ao, unsigned short* __restrict__ bo,
                            int n4) {
  int i = blockIdx.x * 256 + threadIdx.x;
  if (i < n4) {
    float4 x = ((const float4*)a)[i];
    ushort4 y; y.x = f2bf(x.x); y.y = f2bf(x.y); y.z = f2bf(x.z); y.w = f2bf(x.w);
    ((ushort4*)ao)[i] = y;
  } else {
    int j = i - n4;
    float4 x = ((const float4*)b)[j];
    ushort4 y; y.x = f2bf(x.x); y.y = f2bf(x.y); y.z = f2bf(x.z); y.w = f2bf(x.w);
    ((ushort4*)bo)[j] = y;
  }
}

// ---- W (K,N) fp32 -> Wt (N,K) bf16, 32x32 LDS tile transpose ----
__global__ void wtrans_kernel(const float* __restrict__ Wq, const float* __restrict__ Wk,
                              unsigned short* __restrict__ Wqt, unsigned short* __restrict__ Wkt) {
  const float* W = blockIdx.z ? Wk : Wq;
  unsigned short* Wt = blockIdx.z ? Wkt : Wqt;
  __shared__ unsigned short tile[32][33];
  int k0 = blockIdx.x * 32, n0 = blockIdx.y * 32;
  int tx = threadIdx.x, ty = threadIdx.y;
  #pragma unroll
  for (int i = 0; i < 4; ++i) {
    int k = ty + i * 8;
    tile[k][tx] = f2bf(W[(size_t)(k0 + k) * 1024 + n0 + tx]);
  }
  __syncthreads();
  #pragma unroll
  for (int i = 0; i < 4; ++i) {
    int n = ty + i * 8;
    Wt[(size_t)(n0 + n) * 1024 + k0 + tx] = tile[tx][n];
  }
}

// ---- per-(b,h): asp(64), aw(64), u[bh,d]=sum_e Wk[d,h*64+e]*aw[e], c=bk.aw ----
// 256 threads: coalesced Wd/Wk reads, wave-cooperative dots + shfl reduce.
__global__ __launch_bounds__(256)
void prep_kernel(const float* __restrict__ aspect, const float* __restrict__ Wd,
                 const float* __restrict__ bd, const float* __restrict__ weight_m,
                 const float* __restrict__ Wk, const float* __restrict__ bk,
                 float* __restrict__ u_out, float* __restrict__ c_out) {
  int bh = blockIdx.x, b = bh >> 4, h = bh & 15;
  int tid = threadIdx.x, e = tid & 63, g = tid >> 6;
  __shared__ float part[4][64];
  __shared__ float asp_s[64];
  __shared__ float aw_s[64];
  const float* arow = aspect + (size_t)b * 1024;
  float acc = 0.f;
  for (int d = g * 256; d < g * 256 + 256; ++d)
    acc += arow[d] * Wd[(size_t)d * 64 + e];   // lanes e consecutive: coalesced
  part[g][e] = acc;
  __syncthreads();
  if (tid < 64)
    asp_s[tid] = bd[tid] + part[0][tid] + part[1][tid] + part[2][tid] + part[3][tid];
  __syncthreads();
  if (tid < 64) {
    const float* wm = weight_m + (size_t)h * 4096;
    float aw = 0.f;
    #pragma unroll 8
    for (int d = 0; d < 64; ++d) aw += asp_s[d] * wm[d * 64 + tid];
    aw_s[tid] = aw;
  }
  __syncthreads();
  float awl = aw_s[e];
  if (g == 0) {
    float s = bk[h * 64 + e] * awl;
    #pragma unroll
    for (int off = 32; off >= 1; off >>= 1) s += __shfl_xor(s, off, 64);
    if (e == 0) c_out[bh] = s;
  }
  // u rows: each wave does 2 rows per iter; lane reads Wk[d, h*64+e] (256 B coalesced)
  for (int d0 = g * 2; d0 < 1024; d0 += 8) {
    float s0 = Wk[(size_t)d0 * 1024 + h * 64 + e] * awl;
    float s1 = Wk[(size_t)(d0 + 1) * 1024 + h * 64 + e] * awl;
    #pragma unroll
    for (int off = 32; off >= 1; off >>= 1) {
      s0 += __shfl_xor(s0, off, 64);
      s1 += __shfl_xor(s1, off, 64);
    }
    if (e == 0) {
      u_out[(size_t)bh * 1024 + d0]     = s0;
      u_out[(size_t)bh * 1024 + d0 + 1] = s1;
    }
  }
}

// ---- mask (B,S,S) int32 -> bitmask, 64 bits per ballot ----
__global__ void bitmask_kernel(const int* __restrict__ mask, unsigned long long* __restrict__ mb) {
  int gw = (blockIdx.x * 256 + threadIdx.x) >> 6;   // 1024 waves
  int lane = threadIdx.x & 63;
  for (int row = gw; row < 4096; row += 1024) {
    const int* mr = mask + (size_t)row * 512;
    unsigned long long* dst = mb + (size_t)row * 8;
    #pragma unroll
    for (int it = 0; it < 8; ++it) {
      int m = mr[it * 64 + lane];
      unsigned long long bb = __ballot(m != 0);
      if (lane == 0) dst[it] = bb;
    }
  }
}

// ---- v[b,h,t] = tanh(key_in[b,t,:].u[b,h,:] + c[b,h] + bias_m), fp32 exact ----
// Block = (b, 8 rows). Rows staged in LDS (coalesced); u read lane-consecutive from L2.
__global__ __launch_bounds__(256)
void v_kernel(const float* __restrict__ key_in, const float* __restrict__ u,
              const float* __restrict__ c, const float* __restrict__ bias_m,
              float* __restrict__ v) {
  __shared__ float ks_[8][1024];  // 32 KB
  int b = blockIdx.y, t0 = blockIdx.x * 8;
  int tid = threadIdx.x, wid = tid >> 6, lane = tid & 63;
  const float4* ksrc = (const float4*)(key_in + ((size_t)b * 512 + t0) * 1024);
  float4* kdst = (float4*)&ks_[0][0];
  for (int i = tid; i < 2048; i += 256) kdst[i] = ksrc[i];
  __syncthreads();
  const float* ub = u + (size_t)b * 16384;
  int r0 = wid * 2;
  float acc0[16] = {}, acc1[16] = {};
  for (int i = 0; i < 16; ++i) {
    int col = lane + 64 * i;
    float kv0 = ks_[r0][col], kv1 = ks_[r0 + 1][col];
    #pragma unroll
    for (int h = 0; h < 16; ++h) {
      float uv = ub[h * 1024 + col];
      acc0[h] += kv0 * uv;
      acc1[h] += kv1 * uv;
    }
  }
  float cb = bias_m[0];
  #pragma unroll
  for (int h = 0; h < 16; ++h) {
    float a0 = acc0[h], a1 = acc1[h];
    #pragma unroll
    for (int off = 32; off >= 1; off >>= 1) {
      a0 += __shfl_xor(a0, off, 64);
      a1 += __shfl_xor(a1, off, 64);
    }
    if (lane == h) {
      int bh = b * 16 + h;
      float cc = c[bh] + cb;
      v[(size_t)bh * 512 + t0 + r0]     = tanhf(a0 + cc);
      v[(size_t)bh * 512 + t0 + r0 + 1] = tanhf(a1 + cc);
    }
  }
}

// ---- a_sc fill (lastocc computed inline), nontemporal float4 writes ----
__global__ void asc_kernel(const float* __restrict__ v, const int* __restrict__ ids,
                           float* __restrict__ out) {
  size_t i4 = (size_t)blockIdx.x * 256 + threadIdx.x;  // float4 index
  int t0 = (int)(i4 & 127) * 4;
  int s  = (int)(i4 >> 7) & 511;
  int bh = (int)(i4 >> 16);
  int b  = bh >> 4;
  int i0 = ids[b * 4], i1 = ids[b * 4 + 1], i2 = ids[b * 4 + 2], i3 = ids[b * 4 + 3];
  #define LASTOF(t) ((i3==(t))?3:(i2==(t))?2:(i1==(t))?1:(i0==(t))?0:-1)
  int ls  = LASTOF(s);
  int lt0 = LASTOF(t0), lt1 = LASTOF(t0+1), lt2 = LASTOF(t0+2), lt3 = LASTOF(t0+3);
  #undef LASTOF
  const float* vrow = v + (size_t)bh * 512;
  float vs = vrow[s];
  float4 vt = *(const float4*)(vrow + t0);
  f32x4 o;
  o[0] = (lt0 >= 0 && lt0 >= ls) ? vs : vt.x;
  o[1] = (lt1 >= 0 && lt1 >= ls) ? vs : vt.y;
  o[2] = (lt2 >= 0 && lt2 >= ls) ? vs : vt.z;
  o[3] = (lt3 >= 0 && lt3 >= ls) ? vs : vt.w;
  __builtin_nontemporal_store(o, ((f32x4*)out) + i4);
}

// ---- bf16 MFMA GEMM: C(4096x1024) = A @ Bt^T, scatter to (B,H,S,DK) bf16 + bias ----
__global__ __launch_bounds__(256, 2)
void gemm_kernel(const unsigned short* __restrict__ Aq, const unsigned short* __restrict__ Ak,
                 const unsigned short* __restrict__ Bq, const unsigned short* __restrict__ Bk,
                 const float* __restrict__ bq, const float* __restrict__ bk,
                 unsigned short* __restrict__ qb, unsigned short* __restrict__ kb) {
  const unsigned short* A  = blockIdx.z ? Ak : Aq;
  const unsigned short* Bt = blockIdx.z ? Bk : Bq;
  const float* bias = blockIdx.z ? bk : bq;
  unsigned short* out = blockIdx.z ? kb : qb;
  const int m0 = blockIdx.y * 128, n0 = blockIdx.x * 128;
  __shared__ __align__(16) unsigned short As[128 * 32];
  __shared__ __align__(16) unsigned short Bs[128 * 32];
  const int tid = threadIdx.x, wid = tid >> 6, lane = tid & 63;
  const int wr = wid >> 1, wc = wid & 1;
  const int quad = lane >> 4, l15 = lane & 15;
  const int rstage = lane >> 2;
  const int kc = (lane & 3) * 8;
  f32x4 acc[4][4] = {};
  for (int k0 = 0; k0 < 1024; k0 += 32) {
    #pragma unroll
    for (int i = 0; i < 2; ++i) {
      int row = wid * 32 + i * 16 + rstage;
      gload_lds16(A  + (size_t)(m0 + row) * 1024 + k0 + kc, As + (wid * 32 + i * 16) * 32);
      gload_lds16(Bt + (size_t)(n0 + row) * 1024 + k0 + kc, Bs + (wid * 32 + i * 16) * 32);
    }
    __syncthreads();
    bf16x8 af[4], bfr[4];
    #pragma unroll
    for (int mi = 0; mi < 4; ++mi)
      af[mi] = *(const bf16x8*)(As + (wr * 64 + mi * 16 + l15) * 32 + quad * 8);
    #pragma unroll
    for (int ni = 0; ni < 4; ++ni)
      bfr[ni] = *(const bf16x8*)(Bs + (wc * 64 + ni * 16 + l15) * 32 + quad * 8);
    #pragma unroll
    for (int mi = 0; mi < 4; ++mi)
      #pragma unroll
      for (int ni = 0; ni < 4; ++ni)
        acc[mi][ni] = __builtin_amdgcn_mfma_f32_16x16x32_bf16(af[mi], bfr[ni], acc[mi][ni], 0, 0, 0);
    __syncthreads();
  }
  #pragma unroll
  for (int mi = 0; mi < 4; ++mi) {
    #pragma unroll
    for (int ni = 0; ni < 4; ++ni) {
      const int n = n0 + wc * 64 + ni * 16 + l15;
      const int hh = n >> 6, dk = n & 63;
      const float bv = bias[n];
      #pragma unroll
      for (int r = 0; r < 4; ++r) {
        const int m = m0 + wr * 64 + mi * 16 + quad * 4 + r;
        const int bb = m >> 9, ss = m & 511;
        out[(((size_t)bb * 16 + hh) * 512 + ss) * 64 + dk] = f2bf(acc[mi][ni][r] + bv);
      }
    }
  }
}

// ---- scores + bitmask + softmax; block = (b,h,64 s-rows), wave = 16 rows x 512 cols ----
__global__ __launch_bounds__(256, 2)
void attn_kernel(const unsigned short* __restrict__ qb, const unsigned short* __restrict__ kb,
                 const unsigned* __restrict__ mbits, float* __restrict__ attn) {
  __shared__ __align__(16) unsigned short ks[256 * 64];  // 32 KB
  __shared__ __align__(16) unsigned short qs[64 * 64];   // 8 KB
  const int s0 = blockIdx.x * 64;
  const int h = blockIdx.y, b = blockIdx.z, bh = b * 16 + h;
  const int tid = threadIdx.x, wid = tid >> 6, lane = tid & 63;
  const int quad = lane >> 4, l15 = lane & 15;
  const unsigned short* kslab = kb + (size_t)bh * 512 * 64;
  const unsigned short* qslab = qb + ((size_t)bh * 512 + s0) * 64;
  #pragma unroll
  for (int i = 0; i < 2; ++i)
    gload_lds16(qslab + (wid * 2 + i) * 512 + lane * 8, qs + (wid * 2 + i) * 512);
  #pragma unroll
  for (int i = 0; i < 8; ++i)
    gload_lds16(kslab + (wid * 8 + i) * 512 + lane * 8, ks + (wid * 8 + i) * 512);
  __syncthreads();
  bf16x8 af0 = *(const bf16x8*)(qs + (wid * 16 + l15) * 64 + quad * 8);
  bf16x8 af1 = *(const bf16x8*)(qs + (wid * 16 + l15) * 64 + 32 + quad * 8);
  f32x4 acc[32];
  #pragma unroll
  for (int tile = 0; tile < 16; ++tile) {
    bf16x8 b0 = *(const bf16x8*)(ks + (tile * 16 + l15) * 64 + quad * 8);
    bf16x8 b1 = *(const bf16x8*)(ks + (tile * 16 + l15) * 64 + 32 + quad * 8);
    f32x4 a = {0.f, 0.f, 0.f, 0.f};
    a = __builtin_amdgcn_mfma_f32_16x16x32_bf16(af0, b0, a, 0, 0, 0);
    a = __builtin_amdgcn_mfma_f32_16x16x32_bf16(af1, b1, a, 0, 0, 0);
    acc[tile] = a;
  }
  __syncthreads();
  #pragma unroll
  for (int i = 0; i < 8; ++i)
    gload_lds16(kslab + 16384 + (wid * 8 + i) * 512 + lane * 8, ks + (wid * 8 + i) * 512);
  __syncthreads();
  #pragma unroll
  for (int tile = 16; tile < 32; ++tile) {
    int tl = tile - 16;
    bf16x8 b0 = *(const bf16x8*)(ks + (tl * 16 + l15) * 64 + quad * 8);
    bf16x8 b1 = *(const bf16x8*)(ks + (tl * 16 + l15) * 64 + 32 + quad * 8);
    f32x4 a = {0.f, 0.f, 0.f, 0.f};
    a = __builtin_amdgcn_mfma_f32_16x16x32_bf16(af0, b0, a, 0, 0, 0);
    a = __builtin_amdgcn_mfma_f32_16x16x32_bf16(af1, b1, a, 0, 0, 0);
    acc[tile] = a;
  }
  // scale + bitmask + row-max (row = s0 + wid*16 + quad*4 + r, col = tile*16 + l15)
  const size_t srow = (size_t)s0 + wid * 16 + quad * 4;
  const unsigned* mrow = mbits + ((size_t)b * 512 + srow) * 16;  // 16 u32 words per row
  float mx[4] = {-3.0e38f, -3.0e38f, -3.0e38f, -3.0e38f};
  #pragma unroll
  for (int tp = 0; tp < 16; ++tp) {
    #pragma unroll
    for (int r = 0; r < 4; ++r) {
      unsigned m = mrow[(size_t)r * 16 + tp];
      float sc0 = acc[2 * tp][r] * 0.125f;
      float sc1 = acc[2 * tp + 1][r] * 0.125f;
      sc0 = ((m >> l15) & 1u) ? sc0 : -1.0e9f;
      sc1 = ((m >> (16 + l15)) & 1u) ? sc1 : -1.0e9f;
      acc[2 * tp][r] = sc0;
      acc[2 * tp + 1][r] = sc1;
      mx[r] = fmaxf(mx[r], fmaxf(sc0, sc1));
    }
  }
  #pragma unroll
  for (int r = 0; r < 4; ++r)
    #pragma unroll
    for (int off = 1; off < 16; off <<= 1)
      mx[r] = fmaxf(mx[r], __shfl_xor(mx[r], off, 64));
  float sm[4] = {0.f, 0.f, 0.f, 0.f};
  #pragma unroll
  for (int tile = 0; tile < 32; ++tile)
    #pragma unroll
    for (int r = 0; r < 4; ++r) {
      float e = __expf(acc[tile][r] - mx[r]);
      acc[tile][r] = e;
      sm[r] += e;
    }
  #pragma unroll
  for (int r = 0; r < 4; ++r) {
    #pragma unroll
    for (int off = 1; off < 16; off <<= 1)
      sm[r] += __shfl_xor(sm[r], off, 64);
    sm[r] = 1.0f / sm[r];
  }
  float* obase = attn + ((size_t)bh * 512 + srow) * 512 + l15;
  #pragma unroll
  for (int r = 0; r < 4; ++r)
    #pragma unroll
    for (int tile = 0; tile < 32; ++tile)
      __builtin_nontemporal_store(acc[tile][r] * sm[r], &obase[(size_t)r * 512 + tile * 16]);
}

extern "C" void kernel_launch(void* const* d_in, const int* in_sizes, int n_in,
                              void* d_out, int out_size, void* d_ws, size_t ws_size,
                              hipStream_t stream) {
  const float* query    = (const float*)d_in[0];
  const float* key_in   = (const float*)d_in[1];
  const int*   mask     = (const int*)d_in[2];
  const float* aspect   = (const float*)d_in[3];
  const int*   a_ids    = (const int*)d_in[4];
  const float* Wq       = (const float*)d_in[5];
  const float* bq       = (const float*)d_in[6];
  const float* Wk       = (const float*)d_in[7];
  const float* bk       = (const float*)d_in[8];
  const float* Wd       = (const float*)d_in[9];
  const float* bd       = (const float*)d_in[10];
  const float* weight_m = (const float*)d_in[11];
  const float* bias_m   = (const float*)d_in[12];

  float* out_asc  = (float*)d_out;
  float* out_attn = out_asc + 33554432ull;  // B*H*S*S

  char* ws = (char*)d_ws;
  unsigned short* Aq   = (unsigned short*)(ws);                 // 8 MB  bf16 query
  unsigned short* Ak   = (unsigned short*)(ws + 8388608);       // 8 MB  bf16 key_in
  unsigned short* Wqt  = (unsigned short*)(ws + 16777216);      // 2 MB  bf16 Wq^T
  unsigned short* Wkt  = (unsigned short*)(ws + 18874368);      // 2 MB  bf16 Wk^T
  unsigned short* qbuf = (unsigned short*)(ws + 20971520);      // 8 MB  q (B,H,S,DK)
  unsigned short* kbuf = (unsigned short*)(ws + 29360128);      // 8 MB  k (B,H,S,DK)
  float* u   = (float*)(ws + 37748736);                         // 512 KB
  float* c   = (float*)(ws + 38273024);                         // 4 KB pad
  float* v   = (float*)(ws + 38277120);                         // 256 KB
  unsigned long long* mb = (unsigned long long*)(ws + 38539264);// 256 KB bitmask

  conv_kernel<<<dim3(8192), dim3(256), 0, stream>>>(query, key_in, Aq, Ak, 1048576);
  wtrans_kernel<<<dim3(32, 32, 2), dim3(32, 8), 0, stream>>>(Wq, Wk, Wqt, Wkt);
  prep_kernel<<<dim3(128), dim3(256), 0, stream>>>(aspect, Wd, bd, weight_m, Wk, bk, u, c);
  bitmask_kernel<<<dim3(256), dim3(256), 0, stream>>>(mask, mb);
  gemm_kernel<<<dim3(8, 32, 2), dim3(256), 0, stream>>>(Aq, Ak, Wqt, Wkt, bq, bk, qbuf, kbuf);
  v_kernel<<<dim3(64, 8), dim3(256), 0, stream>>>(key_in, u, c, bias_m, v);
  asc_kernel<<<dim3(32768), dim3(256), 0, stream>>>(v, a_ids, out_asc);
  attn_kernel<<<dim3(8, 16, 8), dim3(256), 0, stream>>>(qbuf, kbuf, (const unsigned*)mb, out_attn);
}

// Round 3
// 425.197 us; speedup vs baseline: 1.2785x; 1.1473x over previous
//
#include <hip/hip_runtime.h>

// B=8, S=512, D=1024, H=16, DK=64
typedef __bf16 bf16x8 __attribute__((ext_vector_type(8)));
typedef float  f32x4  __attribute__((ext_vector_type(4)));

__device__ __forceinline__ unsigned short f2bf(float f) {
  union { float f; unsigned u; } x; x.f = f;
  unsigned r = (x.u + 0x7FFFu + ((x.u >> 16) & 1u)) >> 16;  // RNE
  return (unsigned short)r;
}

__device__ __forceinline__ void gload_lds16(const void* g, void* l) {
  __builtin_amdgcn_global_load_lds((__attribute__((address_space(1))) void*)g,
                                   (__attribute__((address_space(3))) void*)l,
                                   16, 0, 0);
}

// ---- fp32 -> bf16 flat convert for query & key_in (n4 float4's each) ----
__global__ void conv_kernel(const float* __restrict__ a, const float* __restrict__ b,
                            unsigned short* __restrict__ ao, unsigned short* __restrict__ bo,
                            int n4) {
  int i = blockIdx.x * 256 + threadIdx.x;
  if (i < n4) {
    float4 x = ((const float4*)a)[i];
    ushort4 y; y.x = f2bf(x.x); y.y = f2bf(x.y); y.z = f2bf(x.z); y.w = f2bf(x.w);
    ((ushort4*)ao)[i] = y;
  } else {
    int j = i - n4;
    float4 x = ((const float4*)b)[j];
    ushort4 y; y.x = f2bf(x.x); y.y = f2bf(x.y); y.z = f2bf(x.z); y.w = f2bf(x.w);
    ((ushort4*)bo)[j] = y;
  }
}

// ---- W (K,N) fp32 -> Wt (N,K) bf16, 32x32 LDS tile transpose ----
__global__ void wtrans_kernel(const float* __restrict__ Wq, const float* __restrict__ Wk,
                              unsigned short* __restrict__ Wqt, unsigned short* __restrict__ Wkt) {
  const float* W = blockIdx.z ? Wk : Wq;
  unsigned short* Wt = blockIdx.z ? Wkt : Wqt;
  __shared__ unsigned short tile[32][33];
  int k0 = blockIdx.x * 32, n0 = blockIdx.y * 32;
  int tx = threadIdx.x, ty = threadIdx.y;
  #pragma unroll
  for (int i = 0; i < 4; ++i) {
    int k = ty + i * 8;
    tile[k][tx] = f2bf(W[(size_t)(k0 + k) * 1024 + n0 + tx]);
  }
  __syncthreads();
  #pragma unroll
  for (int i = 0; i < 4; ++i) {
    int n = ty + i * 8;
    Wt[(size_t)(n0 + n) * 1024 + k0 + tx] = tile[tx][n];
  }
}

// ---- prep_aw: per-(b,h) asp(64) -> aw(64), c = bk.aw ----
__global__ __launch_bounds__(256)
void prep_aw_kernel(const float* __restrict__ aspect, const float* __restrict__ Wd,
                    const float* __restrict__ bd, const float* __restrict__ weight_m,
                    const float* __restrict__ bk,
                    float* __restrict__ aw_out, float* __restrict__ c_out) {
  int bh = blockIdx.x, b = bh >> 4, h = bh & 15;
  int tid = threadIdx.x, e = tid & 63, g = tid >> 6;
  __shared__ float part[4][64];
  __shared__ float asp_s[64];
  __shared__ float aw_s[64];
  const float* arow = aspect + (size_t)b * 1024;
  float acc = 0.f;
  for (int d = g * 256; d < g * 256 + 256; ++d)
    acc += arow[d] * Wd[(size_t)d * 64 + e];
  part[g][e] = acc;
  __syncthreads();
  if (tid < 64)
    asp_s[tid] = bd[tid] + part[0][tid] + part[1][tid] + part[2][tid] + part[3][tid];
  __syncthreads();
  if (tid < 64) {
    const float* wm = weight_m + (size_t)h * 4096;
    float aw = 0.f;
    #pragma unroll 8
    for (int d = 0; d < 64; ++d) aw += asp_s[d] * wm[d * 64 + tid];
    aw_s[tid] = aw;
    aw_out[(size_t)bh * 64 + tid] = aw;
  }
  __syncthreads();
  if (g == 0) {
    float s = bk[h * 64 + e] * aw_s[e];
    #pragma unroll
    for (int off = 32; off >= 1; off >>= 1) s += __shfl_xor(s, off, 64);
    if (e == 0) c_out[bh] = s;
  }
}

// ---- prep_u: u[bh,d] = sum_e Wk[d, h*64+e] * aw[bh,e]; 1024 blocks ----
__global__ __launch_bounds__(256)
void prep_u_kernel(const float* __restrict__ Wk, const float* __restrict__ aw_in,
                   float* __restrict__ u_out) {
  int bh = blockIdx.y, h = bh & 15;
  int dbase = blockIdx.x * 128;
  int tid = threadIdx.x, e = tid & 63, g = tid >> 6;
  float awl = aw_in[(size_t)bh * 64 + e];
  #pragma unroll 4
  for (int it = 0; it < 16; ++it) {
    int d0 = dbase + g * 32 + it * 2;
    float s0 = Wk[(size_t)d0 * 1024 + h * 64 + e] * awl;
    float s1 = Wk[(size_t)(d0 + 1) * 1024 + h * 64 + e] * awl;
    #pragma unroll
    for (int off = 32; off >= 1; off >>= 1) {
      s0 += __shfl_xor(s0, off, 64);
      s1 += __shfl_xor(s1, off, 64);
    }
    if (e == 0) {
      u_out[(size_t)bh * 1024 + d0]     = s0;
      u_out[(size_t)bh * 1024 + d0 + 1] = s1;
    }
  }
}

// ---- mask (B,S,S) int32 -> bitmask, 64 bits per ballot ----
__global__ void bitmask_kernel(const int* __restrict__ mask, unsigned long long* __restrict__ mb) {
  int gw = (blockIdx.x * 256 + threadIdx.x) >> 6;   // 1024 waves
  int lane = threadIdx.x & 63;
  for (int row = gw; row < 4096; row += 1024) {
    const int* mr = mask + (size_t)row * 512;
    unsigned long long* dst = mb + (size_t)row * 8;
    #pragma unroll
    for (int it = 0; it < 8; ++it) {
      int m = mr[it * 64 + lane];
      unsigned long long bb = __ballot(m != 0);
      if (lane == 0) dst[it] = bb;
    }
  }
}

// ---- v[b,h,t] = tanh(key_in[b,t,:].u[b,h,:] + c[b,h] + bias_m), fp32 exact ----
__global__ __launch_bounds__(256)
void v_kernel(const float* __restrict__ key_in, const float* __restrict__ u,
              const float* __restrict__ c, const float* __restrict__ bias_m,
              float* __restrict__ v) {
  __shared__ float ks_[8][1024];  // 32 KB
  int b = blockIdx.y, t0 = blockIdx.x * 8;
  int tid = threadIdx.x, wid = tid >> 6, lane = tid & 63;
  const float4* ksrc = (const float4*)(key_in + ((size_t)b * 512 + t0) * 1024);
  float4* kdst = (float4*)&ks_[0][0];
  for (int i = tid; i < 2048; i += 256) kdst[i] = ksrc[i];
  __syncthreads();
  const float* ub = u + (size_t)b * 16384;
  int r0 = wid * 2;
  float acc0[16] = {}, acc1[16] = {};
  for (int i = 0; i < 16; ++i) {
    int col = lane + 64 * i;
    float kv0 = ks_[r0][col], kv1 = ks_[r0 + 1][col];
    #pragma unroll
    for (int h = 0; h < 16; ++h) {
      float uv = ub[h * 1024 + col];
      acc0[h] += kv0 * uv;
      acc1[h] += kv1 * uv;
    }
  }
  float cb = bias_m[0];
  #pragma unroll
  for (int h = 0; h < 16; ++h) {
    float a0 = acc0[h], a1 = acc1[h];
    #pragma unroll
    for (int off = 32; off >= 1; off >>= 1) {
      a0 += __shfl_xor(a0, off, 64);
      a1 += __shfl_xor(a1, off, 64);
    }
    if (lane == h) {
      int bh = b * 16 + h;
      float cc = c[bh] + cb;
      v[(size_t)bh * 512 + t0 + r0]     = tanhf(a0 + cc);
      v[(size_t)bh * 512 + t0 + r0 + 1] = tanhf(a1 + cc);
    }
  }
}

// ---- a_sc fill (lastocc computed inline), nontemporal float4 writes ----
__global__ void asc_kernel(const float* __restrict__ v, const int* __restrict__ ids,
                           float* __restrict__ out) {
  size_t i4 = (size_t)blockIdx.x * 256 + threadIdx.x;  // float4 index
  int t0 = (int)(i4 & 127) * 4;
  int s  = (int)(i4 >> 7) & 511;
  int bh = (int)(i4 >> 16);
  int b  = bh >> 4;
  int i0 = ids[b * 4], i1 = ids[b * 4 + 1], i2 = ids[b * 4 + 2], i3 = ids[b * 4 + 3];
  #define LASTOF(t) ((i3==(t))?3:(i2==(t))?2:(i1==(t))?1:(i0==(t))?0:-1)
  int ls  = LASTOF(s);
  int lt0 = LASTOF(t0), lt1 = LASTOF(t0+1), lt2 = LASTOF(t0+2), lt3 = LASTOF(t0+3);
  #undef LASTOF
  const float* vrow = v + (size_t)bh * 512;
  float vs = vrow[s];
  float4 vt = *(const float4*)(vrow + t0);
  f32x4 o;
  o[0] = (lt0 >= 0 && lt0 >= ls) ? vs : vt.x;
  o[1] = (lt1 >= 0 && lt1 >= ls) ? vs : vt.y;
  o[2] = (lt2 >= 0 && lt2 >= ls) ? vs : vt.z;
  o[3] = (lt3 >= 0 && lt3 >= ls) ? vs : vt.w;
  __builtin_nontemporal_store(o, ((f32x4*)out) + i4);
}

// ---- bf16 MFMA GEMM, BK=64, XOR-swizzled LDS (2-way conflicts = free) ----
// grid (32 m-tiles, 8 n-tiles, 2 gemms); x = m so A-tile reuse is XCD-local.
__global__ __launch_bounds__(256, 2)
void gemm_kernel(const unsigned short* __restrict__ Aq, const unsigned short* __restrict__ Ak,
                 const unsigned short* __restrict__ Bq, const unsigned short* __restrict__ Bk,
                 const float* __restrict__ bq, const float* __restrict__ bk,
                 unsigned short* __restrict__ qb, unsigned short* __restrict__ kb) {
  const unsigned short* A  = blockIdx.z ? Ak : Aq;
  const unsigned short* Bt = blockIdx.z ? Bk : Bq;
  const float* bias = blockIdx.z ? bk : bq;
  unsigned short* out = blockIdx.z ? kb : qb;
  const int m0 = blockIdx.x * 128, n0 = blockIdx.y * 128;
  __shared__ __align__(16) unsigned short As[128 * 64];  // 16 KB
  __shared__ __align__(16) unsigned short Bs[128 * 64];
  const int tid = threadIdx.x, wid = tid >> 6, lane = tid & 63;
  const int wr = wid >> 1, wc = wid & 1;
  const int quad = lane >> 4, l15 = lane & 15;
  const int srw = lane >> 3;                      // row within 8-row chunk
  const int jcol = ((lane & 7) ^ srw) * 8;        // swizzled logical elem offset
  const int p0 = (quad ^ (l15 & 7)) * 8;          // physical offset for frag j=quad
  f32x4 acc[4][4] = {};
  for (int k0 = 0; k0 < 1024; k0 += 64) {
    #pragma unroll
    for (int i = 0; i < 4; ++i) {
      int r = wid * 32 + i * 8 + srw;
      gload_lds16(A  + (size_t)(m0 + r) * 1024 + k0 + jcol, As + (wid * 32 + i * 8) * 64);
      gload_lds16(Bt + (size_t)(n0 + r) * 1024 + k0 + jcol, Bs + (wid * 32 + i * 8) * 64);
    }
    __syncthreads();
    bf16x8 af[4][2], bfr[4][2];
    #pragma unroll
    for (int mi = 0; mi < 4; ++mi) {
      const unsigned short* base = As + (wr * 64 + mi * 16 + l15) * 64;
      af[mi][0] = *(const bf16x8*)(base + p0);
      af[mi][1] = *(const bf16x8*)(base + (p0 ^ 32));
    }
    #pragma unroll
    for (int ni = 0; ni < 4; ++ni) {
      const unsigned short* base = Bs + (wc * 64 + ni * 16 + l15) * 64;
      bfr[ni][0] = *(const bf16x8*)(base + p0);
      bfr[ni][1] = *(const bf16x8*)(base + (p0 ^ 32));
    }
    #pragma unroll
    for (int mi = 0; mi < 4; ++mi)
      #pragma unroll
      for (int ni = 0; ni < 4; ++ni) {
        acc[mi][ni] = __builtin_amdgcn_mfma_f32_16x16x32_bf16(af[mi][0], bfr[ni][0], acc[mi][ni], 0, 0, 0);
        acc[mi][ni] = __builtin_amdgcn_mfma_f32_16x16x32_bf16(af[mi][1], bfr[ni][1], acc[mi][ni], 0, 0, 0);
      }
    __syncthreads();
  }
  #pragma unroll
  for (int mi = 0; mi < 4; ++mi) {
    #pragma unroll
    for (int ni = 0; ni < 4; ++ni) {
      const int n = n0 + wc * 64 + ni * 16 + l15;
      const int hh = n >> 6, dk = n & 63;
      const float bv = bias[n];
      #pragma unroll
      for (int r = 0; r < 4; ++r) {
        const int m = m0 + wr * 64 + mi * 16 + quad * 4 + r;
        const int bb = m >> 9, ss = m & 511;
        out[(((size_t)bb * 16 + hh) * 512 + ss) * 64 + dk] = f2bf(acc[mi][ni][r] + bv);
      }
    }
  }
}

// ---- scores + bitmask + softmax; grid (128 bh, 8 s-tiles) for XCD k-locality ----
__global__ __launch_bounds__(256, 2)
void attn_kernel(const unsigned short* __restrict__ qb, const unsigned short* __restrict__ kb,
                 const unsigned* __restrict__ mbits, float* __restrict__ attn) {
  __shared__ __align__(16) unsigned short ks[256 * 64];  // 32 KB (half of k slab)
  __shared__ __align__(16) unsigned short qs[64 * 64];   // 8 KB
  const int bh = blockIdx.x, b = bh >> 4;
  const int s0 = blockIdx.y * 64;
  const int tid = threadIdx.x, wid = tid >> 6, lane = tid & 63;
  const int quad = lane >> 4, l15 = lane & 15;
  const int srw = lane >> 3;
  const int j8 = ((lane & 7) ^ srw) * 8;          // staging swizzle
  const int p0 = (quad ^ (l15 & 7)) * 8;          // frag-read physical offset
  const unsigned short* kslab = kb + (size_t)bh * 512 * 64;
  const unsigned short* qslab = qb + ((size_t)bh * 512 + s0) * 64;
  #pragma unroll
  for (int i = 0; i < 2; ++i)
    gload_lds16(qslab + (wid * 2 + i) * 512 + srw * 64 + j8, qs + (wid * 2 + i) * 512);
  #pragma unroll
  for (int i = 0; i < 8; ++i)
    gload_lds16(kslab + (wid * 8 + i) * 512 + srw * 64 + j8, ks + (wid * 8 + i) * 512);
  __syncthreads();
  const unsigned short* qbase = qs + (wid * 16 + l15) * 64;
  bf16x8 af0 = *(const bf16x8*)(qbase + p0);
  bf16x8 af1 = *(const bf16x8*)(qbase + (p0 ^ 32));
  f32x4 acc[32];
  #pragma unroll
  for (int tile = 0; tile < 16; ++tile) {
    const unsigned short* kbase = ks + (tile * 16 + l15) * 64;
    bf16x8 b0 = *(const bf16x8*)(kbase + p0);
    bf16x8 b1 = *(const bf16x8*)(kbase + (p0 ^ 32));
    f32x4 a = {0.f, 0.f, 0.f, 0.f};
    a = __builtin_amdgcn_mfma_f32_16x16x32_bf16(af0, b0, a, 0, 0, 0);
    a = __builtin_amdgcn_mfma_f32_16x16x32_bf16(af1, b1, a, 0, 0, 0);
    acc[tile] = a;
  }
  __syncthreads();
  #pragma unroll
  for (int i = 0; i < 8; ++i)
    gload_lds16(kslab + 16384 + (wid * 8 + i) * 512 + srw * 64 + j8, ks + (wid * 8 + i) * 512);
  __syncthreads();
  #pragma unroll
  for (int tile = 16; tile < 32; ++tile) {
    const unsigned short* kbase = ks + ((tile - 16) * 16 + l15) * 64;
    bf16x8 b0 = *(const bf16x8*)(kbase + p0);
    bf16x8 b1 = *(const bf16x8*)(kbase + (p0 ^ 32));
    f32x4 a = {0.f, 0.f, 0.f, 0.f};
    a = __builtin_amdgcn_mfma_f32_16x16x32_bf16(af0, b0, a, 0, 0, 0);
    a = __builtin_amdgcn_mfma_f32_16x16x32_bf16(af1, b1, a, 0, 0, 0);
    acc[tile] = a;
  }
  // scale + bitmask + softmax (row = s0 + wid*16 + quad*4 + r, col = tile*16 + l15)
  const size_t srow = (size_t)s0 + wid * 16 + quad * 4;
  const unsigned* mrow = mbits + ((size_t)b * 512 + srow) * 16;
  float mx[4] = {-3.0e38f, -3.0e38f, -3.0e38f, -3.0e38f};
  #pragma unroll
  for (int tp = 0; tp < 16; ++tp) {
    #pragma unroll
    for (int r = 0; r < 4; ++r) {
      unsigned m = mrow[(size_t)r * 16 + tp];
      float sc0 = acc[2 * tp][r] * 0.125f;
      float sc1 = acc[2 * tp + 1][r] * 0.125f;
      sc0 = ((m >> l15) & 1u) ? sc0 : -1.0e9f;
      sc1 = ((m >> (16 + l15)) & 1u) ? sc1 : -1.0e9f;
      acc[2 * tp][r] = sc0;
      acc[2 * tp + 1][r] = sc1;
      mx[r] = fmaxf(mx[r], fmaxf(sc0, sc1));
    }
  }
  #pragma unroll
  for (int r = 0; r < 4; ++r)
    #pragma unroll
    for (int off = 1; off < 16; off <<= 1)
      mx[r] = fmaxf(mx[r], __shfl_xor(mx[r], off, 64));
  float sm[4] = {0.f, 0.f, 0.f, 0.f};
  #pragma unroll
  for (int tile = 0; tile < 32; ++tile)
    #pragma unroll
    for (int r = 0; r < 4; ++r) {
      float e = __expf(acc[tile][r] - mx[r]);
      acc[tile][r] = e;
      sm[r] += e;
    }
  #pragma unroll
  for (int r = 0; r < 4; ++r) {
    #pragma unroll
    for (int off = 1; off < 16; off <<= 1)
      sm[r] += __shfl_xor(sm[r], off, 64);
    sm[r] = 1.0f / sm[r];
  }
  float* obase = attn + ((size_t)bh * 512 + srow) * 512 + l15;
  #pragma unroll
  for (int r = 0; r < 4; ++r)
    #pragma unroll
    for (int tile = 0; tile < 32; ++tile)
      __builtin_nontemporal_store(acc[tile][r] * sm[r], &obase[(size_t)r * 512 + tile * 16]);
}

extern "C" void kernel_launch(void* const* d_in, const int* in_sizes, int n_in,
                              void* d_out, int out_size, void* d_ws, size_t ws_size,
                              hipStream_t stream) {
  const float* query    = (const float*)d_in[0];
  const float* key_in   = (const float*)d_in[1];
  const int*   mask     = (const int*)d_in[2];
  const float* aspect   = (const float*)d_in[3];
  const int*   a_ids    = (const int*)d_in[4];
  const float* Wq       = (const float*)d_in[5];
  const float* bq       = (const float*)d_in[6];
  const float* Wk       = (const float*)d_in[7];
  const float* bk       = (const float*)d_in[8];
  const float* Wd       = (const float*)d_in[9];
  const float* bd       = (const float*)d_in[10];
  const float* weight_m = (const float*)d_in[11];
  const float* bias_m   = (const float*)d_in[12];

  float* out_asc  = (float*)d_out;
  float* out_attn = out_asc + 33554432ull;  // B*H*S*S

  char* ws = (char*)d_ws;
  unsigned short* Aq   = (unsigned short*)(ws);                 // 8 MB  bf16 query
  unsigned short* Ak   = (unsigned short*)(ws + 8388608);       // 8 MB  bf16 key_in
  unsigned short* Wqt  = (unsigned short*)(ws + 16777216);      // 2 MB  bf16 Wq^T
  unsigned short* Wkt  = (unsigned short*)(ws + 18874368);      // 2 MB  bf16 Wk^T
  unsigned short* qbuf = (unsigned short*)(ws + 20971520);      // 8 MB  q (B,H,S,DK)
  unsigned short* kbuf = (unsigned short*)(ws + 29360128);      // 8 MB  k (B,H,S,DK)
  float* u   = (float*)(ws + 37748736);                         // 512 KB
  float* c   = (float*)(ws + 38273024);                         // 4 KB pad
  float* v   = (float*)(ws + 38277120);                         // 256 KB
  unsigned long long* mb = (unsigned long long*)(ws + 38539264);// 256 KB bitmask
  float* aw  = (float*)(ws + 38801408);                         // 32 KB

  conv_kernel<<<dim3(8192), dim3(256), 0, stream>>>(query, key_in, Aq, Ak, 1048576);
  wtrans_kernel<<<dim3(32, 32, 2), dim3(32, 8), 0, stream>>>(Wq, Wk, Wqt, Wkt);
  prep_aw_kernel<<<dim3(128), dim3(256), 0, stream>>>(aspect, Wd, bd, weight_m, bk, aw, c);
  bitmask_kernel<<<dim3(256), dim3(256), 0, stream>>>(mask, mb);
  prep_u_kernel<<<dim3(8, 128), dim3(256), 0, stream>>>(Wk, aw, u);
  gemm_kernel<<<dim3(32, 8, 2), dim3(256), 0, stream>>>(Aq, Ak, Wqt, Wkt, bq, bk, qbuf, kbuf);
  v_kernel<<<dim3(64, 8), dim3(256), 0, stream>>>(key_in, u, c, bias_m, v);
  asc_kernel<<<dim3(32768), dim3(256), 0, stream>>>(v, a_ids, out_asc);
  attn_kernel<<<dim3(128, 8), dim3(256), 0, stream>>>(qbuf, kbuf, (const unsigned*)mb, out_attn);
}